// Round 7
// baseline (576.435 us; speedup 1.0000x reference)
//
#include <hip/hip_runtime.h>

// B=4, L=256, E=128, H=8, D=16, NU=512, NT=256. All I/O fp32.
// ONE plain dispatch (512 blocks x 256 thr, 2 blocks/CU co-resident) with a
// software grid barrier between 4 phases:
//   A: 9 input projections (+K-transposed stores) + CI transpose + out/dim-proj fold
//   B: ta2du + du2du + uu2du attention (head-split tasks, rank-2 ci correction for uu)
//   C: epilogue y = Cuu@ouu + Cta@ota + Cdu@odu + bias (held in registers) + BN stat atomics
//   D: BN apply + ReLU from registers

struct MegaArgs {
    const float* x[9]; const float* W[9]; const float* bia[9]; float* out[9];
    int Kdim[9]; int transNb[9];     // 0 = row-major out; else n-per-b for [b][e][n] layout
    const float* CIMat; float* cit;
    const float* dim_w; const float* dim_b;
    const float* uu_ow; const float* uu_ob;
    const float* ta_ow; const float* ta_ob;
    const float* du_ow; const float* du_ob;
    float* Cuu; float* Cta; float* Cdu; float* bcomb;
    const float* qd; const float* kbaseT; const float* vbase;
    const float* qta; const float* ktaT; const float* vta;
    const float* qdu; const float* kduT; const float* vdu;
    float* ouu; float* ota; float* odu;
    const float* uu_in_w;
    float* gstat;                    // 256 floats: [0..127] sum, [128..255] sumsq
    unsigned* bar;                   // [0]=arrival counter, [1]=generation (memset 0)
    const float* bn_g; const float* bn_b;
    float* outp;
};

#define GRID_BLKS 512

// Software grid barrier: all blocks co-resident (launch_bounds + grid <= 2*256).
// Agent-scope release/acquire handles cross-XCD L2 writeback/invalidate.
__device__ __forceinline__ void grid_bar(unsigned* cnt, unsigned* gen)
{
    __syncthreads();                 // drains this block's vmcnt -> stores are in L2
    if (threadIdx.x == 0) {
        unsigned g = __hip_atomic_load(gen, __ATOMIC_RELAXED, __HIP_MEMORY_SCOPE_AGENT);
        unsigned prev = __hip_atomic_fetch_add(cnt, 1u, __ATOMIC_ACQ_REL, __HIP_MEMORY_SCOPE_AGENT);
        if (prev == GRID_BLKS - 1u) {
            __hip_atomic_store(cnt, 0u, __ATOMIC_RELAXED, __HIP_MEMORY_SCOPE_AGENT);
            __hip_atomic_fetch_add(gen, 1u, __ATOMIC_RELEASE, __HIP_MEMORY_SCOPE_AGENT);
        } else {
            while (__hip_atomic_load(gen, __ATOMIC_ACQUIRE, __HIP_MEMORY_SCOPE_AGENT) == g)
                __builtin_amdgcn_s_sleep(2);
        }
    }
    __syncthreads();
}

__global__ __launch_bounds__(256, 2) void mega_kernel(MegaArgs A)
{
    __shared__ __align__(16) float smem[8704];   // 34.8 KB
    int bid = blockIdx.x, tid = threadIdx.x;

    // ================= Phase A =================
    for (int t = bid; t < 2560; t += GRID_BLKS) {   // 5 iterations, uniform
        __syncthreads();
        if (t < 1408) {
            // ---- projection: 8 rows per task ----
            int task, mblk;
            if (t < 896) { task = t >> 7; mblk = t & 127; }
            else { int r = t - 896; task = 7 + (r >> 8); mblk = r & 255; }
            int Kd = A.Kdim[task];
            const float* x = A.x[task];
            int m0 = mblk * 8;
            if (Kd == 128) {
                ((float4*)smem)[tid] = ((const float4*)(x + (size_t)m0 * 128))[tid];
            } else {
                for (int i = tid; i < 1024; i += 256) {
                    int r = i >> 7, c = i & 127;
                    smem[i] = (c < Kd) ? x[(size_t)(m0 + r) * Kd + c] : 0.f;
                }
            }
            __syncthreads();
            int e = tid & 127, half = tid >> 7;
            const float4* w4 = (const float4*)(A.W[task] + (size_t)e * 128);
            const float4* xs4 = (const float4*)smem + half * 4 * 32;
            float acc[4];
            float bv = A.bia[task][e];
#pragma unroll
            for (int r = 0; r < 4; ++r) acc[r] = bv;
#pragma unroll 8
            for (int c = 0; c < 32; ++c) {
                float4 w = w4[c];
#pragma unroll
                for (int r = 0; r < 4; ++r) {
                    float4 xv = xs4[r * 32 + c];
                    acc[r] += w.x * xv.x + w.y * xv.y + w.z * xv.z + w.w * xv.w;
                }
            }
            int nb = A.transNb[task];
            float* op = A.out[task];
            if (nb == 0) {
#pragma unroll
                for (int r = 0; r < 4; ++r)
                    op[(size_t)(m0 + half * 4 + r) * 128 + e] = acc[r];
            } else {
                int b = m0 / nb, nloc = m0 - b * nb;
                float* o = op + ((size_t)b * 128 + e) * nb + nloc + half * 4;
                float4 v = { acc[0], acc[1], acc[2], acc[3] };
                *(float4*)o = v;
            }
        } else if (t < 2432) {
            // ---- CI transpose: cit[b][c][n] = CIMat[b][n][c] ----
            int tb = t - 1408;
            int b = tb >> 8, tt = tb & 255;
            int n0 = (tt >> 4) * 32, c0 = (tt & 15) * 32;
            float (*tile)[33] = (float(*)[33])smem;
            int tx = tid & 31, ty = tid >> 5;   // 32 x 8
            const float* src = A.CIMat + (size_t)b * 262144;
            float* dst = A.cit + (size_t)b * 262144;
#pragma unroll
            for (int i = ty; i < 32; i += 8)
                tile[i][tx] = src[(size_t)(n0 + i) * 512 + c0 + tx];
            __syncthreads();
#pragma unroll
            for (int i = ty; i < 32; i += 8)
                dst[(size_t)(c0 + i) * 512 + n0 + tx] = tile[tx][i];
        } else {
            // ---- fold out-projections into dim projection ----
            float* ds = smem;
            float* red = smem + 384;
            int e = t - 2432, k = tid;
            if (k < 128) {
                ds[k]       = A.dim_w[(size_t)e * 384 + k];
                ds[128 + k] = A.dim_w[(size_t)e * 384 + 128 + k];
                ds[256 + k] = A.dim_w[(size_t)e * 384 + 256 + k];
            }
            __syncthreads();
            if (k < 128) {
                float cu = 0.f, ct = 0.f, cd = 0.f;
#pragma unroll 4
                for (int j = 0; j < 128; ++j) {
                    cu += ds[j]       * A.uu_ow[(size_t)j * 128 + k];
                    ct += ds[128 + j] * A.ta_ow[(size_t)j * 128 + k];
                    cd += ds[256 + j] * A.du_ow[(size_t)j * 128 + k];
                }
                A.Cuu[(size_t)e * 128 + k] = cu;
                A.Cta[(size_t)e * 128 + k] = ct;
                A.Cdu[(size_t)e * 128 + k] = cd;
                red[k] = ds[k] * A.uu_ob[k] + ds[128 + k] * A.ta_ob[k] + ds[256 + k] * A.du_ob[k];
            }
            __syncthreads();
            for (int off = 64; off; off >>= 1) {
                if (k < off) red[k] += red[k + off];
                __syncthreads();
            }
            if (k == 0) A.bcomb[e] = A.dim_b[e] + red[0];
        }
    }
    grid_bar(A.bar, A.bar + 1);

    // ================= Phase B =================
    for (int t = bid; t < 2048; t += GRID_BLKS) {   // 4 iterations, uniform
        __syncthreads();
        if (t < 1024) {
            // ---- attn256 (kind 0 = ta, 1 = du): 2 heads x 8 query rows ----
            int kind = t >> 9, idx = t & 511;
            const float* q  = kind ? A.qdu  : A.qta;
            const float* kT = kind ? A.kduT : A.ktaT;
            const float* v  = kind ? A.vdu  : A.vta;
            float* o        = kind ? A.odu  : A.ota;
            int hg = idx & 3, lt = (idx >> 2) & 31, b = idx >> 7;
            int l0 = lt * 8, bl0 = b * 256 + l0;
            float* qs = smem;            // 256
            float* sc = smem + 256;      // 16*256
            float* den = smem + 4352;    // 16
            {
                int l = tid >> 5, d = tid & 31;
                qs[l * 32 + d] = q[(size_t)(bl0 + l) * 128 + hg * 32 + d];
            }
            __syncthreads();
            {
                int n = tid;
                const float* kp = kT + ((size_t)b * 128 + hg * 32) * 256 + n;
                float acc[8][2];
#pragma unroll
                for (int l = 0; l < 8; ++l) { acc[l][0] = 0.f; acc[l][1] = 0.f; }
#pragma unroll 8
                for (int d = 0; d < 32; ++d) {
                    float kv = kp[(size_t)d * 256];
                    int hl = d >> 4;
#pragma unroll
                    for (int l = 0; l < 8; ++l) acc[l][hl] += qs[l * 32 + d] * kv;
                }
#pragma unroll
                for (int hl = 0; hl < 2; ++hl)
#pragma unroll
                    for (int l = 0; l < 8; ++l)
                        sc[(hl * 8 + l) * 256 + n] = acc[l][hl] * 0.25f;
            }
            __syncthreads();
            {
                int g = tid >> 4, j = tid & 15;
                float* row = sc + g * 256;
                float mx = -1e30f;
#pragma unroll 4
                for (int n = j; n < 256; n += 16) mx = fmaxf(mx, row[n]);
#pragma unroll
                for (int off = 8; off; off >>= 1) mx = fmaxf(mx, __shfl_down(mx, off, 16));
                mx = __shfl(mx, 0, 16);
                float s = 0.f;
#pragma unroll 4
                for (int n = j; n < 256; n += 16) {
                    float ev = __expf(row[n] - mx);
                    row[n] = ev; s += ev;
                }
#pragma unroll
                for (int off = 8; off; off >>= 1) s += __shfl_down(s, off, 16);
                if (j == 0) den[g] = s;
            }
            __syncthreads();
            {
                int col = tid & 31, l = tid >> 5;
                int colglob = hg * 32 + col;
                int g = (col >> 4) * 8 + l;
                const float* vcol = v + (size_t)b * 256 * 128 + colglob;
                const float* p = sc + g * 256;
                float acc = 0.f;
#pragma unroll 4
                for (int n = 0; n < 256; ++n) acc += p[n] * vcol[(size_t)n * 128];
                o[(size_t)(bl0 + l) * 128 + colglob] = acc / den[g];
            }
        } else {
            // ---- attn_uu: 2 heads x 4 query rows, N=512, rank-2 ci correction ----
            int idx = t - 1024;
            int hg = idx & 3, lt = (idx >> 2) & 63, b = idx >> 8;
            int l0 = lt * 4, bl0 = b * 256 + l0;
            float* qs   = smem;            // 128
            float* sc   = smem + 128;      // 8*512
            float* ci0s = smem + 4224;     // 2048
            float* ci1s = smem + 6272;     // 2048
            float* qkA  = smem + 8320;     // 8
            float* qkB  = smem + 8328;
            float* den  = smem + 8336;
            float* hs0  = smem + 8344;
            float* hs1  = smem + 8352;
            float* vpart = smem + 8360;    // 256
            if (tid < 128) {
                int l = tid >> 5, d = tid & 31;
                qs[l * 32 + d] = A.qd[(size_t)(bl0 + l) * 128 + hg * 32 + d];
            }
            {
                const float4* s0 = (const float4*)(A.cit + ((size_t)b * 512 + l0) * 512);
                const float4* s1 = (const float4*)(A.cit + ((size_t)b * 512 + 256 + l0) * 512);
                ((float4*)ci0s)[tid] = s0[tid];  ((float4*)ci0s)[tid + 256] = s0[tid + 256];
                ((float4*)ci1s)[tid] = s1[tid];  ((float4*)ci1s)[tid + 256] = s1[tid + 256];
            }
            __syncthreads();
            if (tid < 8) {
                int hl = tid >> 2, l = tid & 3;
                float a = 0.f, c = 0.f;
#pragma unroll
                for (int d = 0; d < 16; ++d) {
                    float qv = qs[l * 32 + hl * 16 + d];
                    int wr = 128 + hg * 32 + hl * 16 + d;
                    a += qv * A.uu_in_w[(size_t)wr * 128 + 126];
                    c += qv * A.uu_in_w[(size_t)wr * 128 + 127];
                }
                qkA[tid] = a; qkB[tid] = c;
            }
            __syncthreads();
            {
                const float* kp = A.kbaseT + ((size_t)b * 128 + hg * 32) * 512 + tid;
                float acc[2][4][2];
#pragma unroll
                for (int r = 0; r < 2; ++r)
#pragma unroll
                    for (int l = 0; l < 4; ++l) { acc[r][l][0] = 0.f; acc[r][l][1] = 0.f; }
#pragma unroll 8
                for (int d = 0; d < 32; ++d) {
                    float kv0 = kp[(size_t)d * 512];
                    float kv1 = kp[(size_t)d * 512 + 256];
                    int hl = d >> 4;
#pragma unroll
                    for (int l = 0; l < 4; ++l) {
                        float qv = qs[l * 32 + d];
                        acc[0][l][hl] += qv * kv0;
                        acc[1][l][hl] += qv * kv1;
                    }
                }
#pragma unroll
                for (int r = 0; r < 2; ++r) {
                    int n = tid + r * 256;
#pragma unroll
                    for (int l = 0; l < 4; ++l) {
                        float c0 = ci0s[l * 512 + n], c1 = ci1s[l * 512 + n];
#pragma unroll
                        for (int hl = 0; hl < 2; ++hl) {
                            int g = hl * 4 + l;
                            sc[g * 512 + n] = (acc[r][l][hl] + c0 * qkA[g] + c1 * qkB[g]) * 0.25f;
                        }
                    }
                }
            }
            __syncthreads();
            {
                int g = tid >> 5, j = tid & 31;
                int l = g & 3;
                float* row = sc + g * 512;
                const float* c0r = ci0s + l * 512;
                const float* c1r = ci1s + l * 512;
                float mx = -1e30f;
#pragma unroll 4
                for (int n = j; n < 512; n += 32) mx = fmaxf(mx, row[n]);
#pragma unroll
                for (int off = 16; off; off >>= 1) mx = fmaxf(mx, __shfl_down(mx, off, 32));
                mx = __shfl(mx, 0, 32);
                float s = 0.f, a0 = 0.f, a1 = 0.f;
#pragma unroll 4
                for (int n = j; n < 512; n += 32) {
                    float ev = __expf(row[n] - mx);
                    row[n] = ev;
                    s += ev; a0 += ev * c0r[n]; a1 += ev * c1r[n];
                }
#pragma unroll
                for (int off = 16; off; off >>= 1) {
                    s  += __shfl_down(s, off, 32);
                    a0 += __shfl_down(a0, off, 32);
                    a1 += __shfl_down(a1, off, 32);
                }
                if (j == 0) { den[g] = s; hs0[g] = a0; hs1[g] = a1; }
            }
            __syncthreads();
            {
                int col = tid & 31, l = (tid >> 5) & 3, half = tid >> 7;
                int colglob = hg * 32 + col;
                int g = (col >> 4) * 4 + l;
                const float* vcol = A.vbase + ((size_t)b * 512 + half * 256) * 128 + colglob;
                const float* p = sc + g * 512 + half * 256;
                float acc = 0.f;
#pragma unroll 4
                for (int n = 0; n < 256; ++n) acc += p[n] * vcol[(size_t)n * 128];
                vpart[half * 128 + (tid & 127)] = acc;
            }
            __syncthreads();
            if (tid < 128) {
                int col = tid & 31, l = tid >> 5;
                int colglob = hg * 32 + col;
                int g = (col >> 4) * 4 + l;
                float sum = vpart[tid] + vpart[128 + tid];
                float wv126 = A.uu_in_w[(size_t)(256 + colglob) * 128 + 126];
                float wv127 = A.uu_in_w[(size_t)(256 + colglob) * 128 + 127];
                A.ouu[(size_t)(bl0 + l) * 128 + colglob] =
                    (sum + hs0[g] * wv126 + hs1[g] * wv127) / den[g];
            }
        }
    }
    grid_bar(A.bar, A.bar + 1);

    // ================= Phase C: epilogue (held in registers) + BN stats =================
    float accC[2] = { 0.f, 0.f };
    int eC = tid & 127, halfC = tid >> 7, m0C = bid * 4;
    if (bid < 256) {
        __syncthreads();
        float* xs = smem;   // 4 rows x 384
        for (int i = tid; i < 1536; i += 256) {
            int r = i / 384, c = i - r * 384;
            float v;
            if (c < 128)      v = A.ouu[(size_t)(m0C + r) * 128 + c];
            else if (c < 256) v = A.ota[(size_t)(m0C + r) * 128 + c - 128];
            else              v = A.odu[(size_t)(m0C + r) * 128 + c - 256];
            xs[i] = v;
        }
        __syncthreads();
        const float4* cu4 = (const float4*)(A.Cuu + (size_t)eC * 128);
        const float4* ct4 = (const float4*)(A.Cta + (size_t)eC * 128);
        const float4* cd4 = (const float4*)(A.Cdu + (size_t)eC * 128);
        const float4* xs4 = (const float4*)xs;   // row pitch 96 float4
        float bc = A.bcomb[eC];
        accC[0] = bc; accC[1] = bc;
        int r0 = halfC * 2;
#pragma unroll 4
        for (int c = 0; c < 32; ++c) {
            float4 a = cu4[c], bb = ct4[c], d = cd4[c];
#pragma unroll
            for (int rr = 0; rr < 2; ++rr) {
                float4 xu = xs4[(r0 + rr) * 96 + c];
                float4 xt = xs4[(r0 + rr) * 96 + 32 + c];
                float4 xd = xs4[(r0 + rr) * 96 + 64 + c];
                accC[rr] += a.x * xu.x + a.y * xu.y + a.z * xu.z + a.w * xu.w
                          + bb.x * xt.x + bb.y * xt.y + bb.z * xt.z + bb.w * xt.w
                          + d.x * xd.x + d.y * xd.y + d.z * xd.z + d.w * xd.w;
            }
        }
        atomicAdd(A.gstat + eC, accC[0] + accC[1]);
        atomicAdd(A.gstat + 128 + eC, accC[0] * accC[0] + accC[1] * accC[1]);
    }
    grid_bar(A.bar, A.bar + 1);

    // ================= Phase D: BN apply + ReLU =================
    if (bid < 256) {
        float mean = A.gstat[eC] * (1.f / 1024.f);
        float var  = A.gstat[128 + eC] * (1.f / 1024.f) - mean * mean;
        float inv  = rsqrtf(var + 1e-5f);
        float g = A.bn_g[eC], bt = A.bn_b[eC];
        int r0 = halfC * 2;
#pragma unroll
        for (int rr = 0; rr < 2; ++rr)
            A.outp[(size_t)(m0C + r0 + rr) * 128 + eC] =
                fmaxf((accC[rr] - mean) * inv * g + bt, 0.f);
    }
}

extern "C" void kernel_launch(void* const* d_in, const int* in_sizes, int n_in,
                              void* d_out, int out_size, void* d_ws, size_t ws_size,
                              hipStream_t stream)
{
    (void)in_sizes; (void)n_in; (void)out_size; (void)ws_size;
    const float* UUMat    = (const float*)d_in[0];
    const float* DUMat    = (const float*)d_in[1];
    const float* TAMat    = (const float*)d_in[2];
    const float* CIMat    = (const float*)d_in[3];
    const float* uu_in_w  = (const float*)d_in[4];
    const float* uu_in_b  = (const float*)d_in[5];
    const float* uu_out_w = (const float*)d_in[6];
    const float* uu_out_b = (const float*)d_in[7];
    const float* ta_in_w  = (const float*)d_in[8];
    const float* ta_in_b  = (const float*)d_in[9];
    const float* ta_out_w = (const float*)d_in[10];
    const float* ta_out_b = (const float*)d_in[11];
    const float* du_in_w  = (const float*)d_in[12];
    const float* du_in_b  = (const float*)d_in[13];
    const float* du_out_w = (const float*)d_in[14];
    const float* du_out_b = (const float*)d_in[15];
    const float* dim_w    = (const float*)d_in[16];
    const float* dim_b    = (const float*)d_in[17];
    const float* bn_g     = (const float*)d_in[18];
    const float* bn_b     = (const float*)d_in[19];

    const int BL = 1024, BN = 2048;
    float* ws0 = (float*)d_ws;
    unsigned* bar = (unsigned*)ws0;               // 2 u32 in a 64-float slot
    float* gstat  = ws0 + 64;                     // 256 floats
    float* ws     = ws0 + 64 + 256;
    float* cit    = ws; ws += (size_t)4 * 512 * 512;
    float* qd     = ws; ws += (size_t)BL * 128;
    float* kbaseT = ws; ws += (size_t)BN * 128;   // [b][128][512]
    float* vbase  = ws; ws += (size_t)BN * 128;
    float* qta    = ws; ws += (size_t)BL * 128;
    float* ktaT   = ws; ws += (size_t)BL * 128;   // [b][128][256]
    float* vta    = ws; ws += (size_t)BL * 128;
    float* qdu    = ws; ws += (size_t)BL * 128;
    float* kduT   = ws; ws += (size_t)BL * 128;   // [b][128][256]
    float* vdu    = ws; ws += (size_t)BL * 128;
    float* ouu    = ws; ws += (size_t)BL * 128;
    float* ota    = ws; ws += (size_t)BL * 128;
    float* odu    = ws; ws += (size_t)BL * 128;
    float* Cuu    = ws; ws += 128 * 128;
    float* Cta    = ws; ws += 128 * 128;
    float* Cdu    = ws; ws += 128 * 128;
    float* bcomb  = ws; ws += 128;

    MegaArgs A;
    A.x[0] = DUMat; A.W[0] = uu_in_w;             A.bia[0] = uu_in_b;       A.out[0] = qd;     A.Kdim[0] = 128; A.transNb[0] = 0;
    A.x[1] = DUMat; A.W[1] = ta_in_w;             A.bia[1] = ta_in_b;       A.out[1] = qta;    A.Kdim[1] = 128; A.transNb[1] = 0;
    A.x[2] = TAMat; A.W[2] = ta_in_w + 128 * 128; A.bia[2] = ta_in_b + 128; A.out[2] = ktaT;   A.Kdim[2] = 128; A.transNb[2] = 256;
    A.x[3] = TAMat; A.W[3] = ta_in_w + 256 * 128; A.bia[3] = ta_in_b + 256; A.out[3] = vta;    A.Kdim[3] = 128; A.transNb[3] = 0;
    A.x[4] = DUMat; A.W[4] = du_in_w;             A.bia[4] = du_in_b;       A.out[4] = qdu;    A.Kdim[4] = 128; A.transNb[4] = 0;
    A.x[5] = DUMat; A.W[5] = du_in_w + 128 * 128; A.bia[5] = du_in_b + 128; A.out[5] = kduT;   A.Kdim[5] = 128; A.transNb[5] = 256;
    A.x[6] = DUMat; A.W[6] = du_in_w + 256 * 128; A.bia[6] = du_in_b + 256; A.out[6] = vdu;    A.Kdim[6] = 128; A.transNb[6] = 0;
    A.x[7] = UUMat; A.W[7] = uu_in_w + 128 * 128; A.bia[7] = uu_in_b + 128; A.out[7] = kbaseT; A.Kdim[7] = 126; A.transNb[7] = 512;
    A.x[8] = UUMat; A.W[8] = uu_in_w + 256 * 128; A.bia[8] = uu_in_b + 256; A.out[8] = vbase;  A.Kdim[8] = 126; A.transNb[8] = 0;
    A.CIMat = CIMat; A.cit = cit;
    A.dim_w = dim_w; A.dim_b = dim_b;
    A.uu_ow = uu_out_w; A.uu_ob = uu_out_b;
    A.ta_ow = ta_out_w; A.ta_ob = ta_out_b;
    A.du_ow = du_out_w; A.du_ob = du_out_b;
    A.Cuu = Cuu; A.Cta = Cta; A.Cdu = Cdu; A.bcomb = bcomb;
    A.qd = qd; A.kbaseT = kbaseT; A.vbase = vbase;
    A.qta = qta; A.ktaT = ktaT; A.vta = vta;
    A.qdu = qdu; A.kduT = kduT; A.vdu = vdu;
    A.ouu = ouu; A.ota = ota; A.odu = odu;
    A.uu_in_w = uu_in_w;
    A.gstat = gstat;
    A.bar = bar;
    A.bn_g = bn_g; A.bn_b = bn_b;
    A.outp = (float*)d_out;

    // zero barrier words + BN stat accumulators (ws is poisoned 0xAA before every call)
    hipMemsetAsync(d_ws, 0, (64 + 256) * sizeof(float), stream);

    hipLaunchKernelGGL(mega_kernel, dim3(GRID_BLKS), dim3(256), 0, stream, A);
}

// Round 8
// 411.612 us; speedup vs baseline: 1.4004x; 1.4004x over previous
//
#include <hip/hip_runtime.h>

// B=4, L=256, E=128, H=8, D=16, NU=512, NT=256. All I/O fp32.
// ONE plain dispatch (512 blocks x 256 thr, 2 blocks/CU co-resident) with a
// DISTRIBUTED software grid barrier (per-block flags, no RMW contention):
//   A: 9 input projections (+K-transposed stores) + CI transpose + out/dim-proj fold
//   B: ta2du + du2du + uu2du attention (head-split tasks, rank-2 ci correction for uu)
//   C: epilogue y = Cuu@ouu + Cta@ota + Cdu@odu + bias (held in registers) + BN stat atomics
//   D: BN apply + ReLU from registers

struct MegaArgs {
    const float* x[9]; const float* W[9]; const float* bia[9]; float* out[9];
    int Kdim[9]; int transNb[9];     // 0 = row-major out; else n-per-b for [b][e][n] layout
    const float* CIMat; float* cit;
    const float* dim_w; const float* dim_b;
    const float* uu_ow; const float* uu_ob;
    const float* ta_ow; const float* ta_ob;
    const float* du_ow; const float* du_ob;
    float* Cuu; float* Cta; float* Cdu; float* bcomb;
    const float* qd; const float* kbaseT; const float* vbase;
    const float* qta; const float* ktaT; const float* vta;
    const float* qdu; const float* kduT; const float* vdu;
    float* ouu; float* ota; float* odu;
    const float* uu_in_w;
    float* gstat;                    // 256 floats: [0..127] sum, [128..255] sumsq
    unsigned* flags;                 // 512 per-block phase flags (memset 0)
    const float* bn_g; const float* bn_b;
    float* outp;
};

#define GRID_BLKS 512

// Distributed sense barrier: block i publishes flags[i]=phase (release), every
// thread polls 2 flags with RELAXED agent loads (parallel reads, no RMW).
// Phase values are monotonically increasing -> no reset race.
__device__ __forceinline__ void grid_bar(unsigned* flags, unsigned phase)
{
    __syncthreads();                 // all block's stores drained (vmcnt 0)
    if (threadIdx.x == 0) {
        __threadfence();             // agent-scope release: L2 writeback
        __hip_atomic_store(flags + blockIdx.x, phase,
                           __ATOMIC_RELAXED, __HIP_MEMORY_SCOPE_AGENT);
    }
    unsigned t = threadIdx.x;
    while (__hip_atomic_load(flags + t, __ATOMIC_RELAXED, __HIP_MEMORY_SCOPE_AGENT) < phase)
        __builtin_amdgcn_s_sleep(1);
    while (__hip_atomic_load(flags + t + 256, __ATOMIC_RELAXED, __HIP_MEMORY_SCOPE_AGENT) < phase)
        __builtin_amdgcn_s_sleep(1);
    __threadfence();                 // agent-scope acquire: invalidate stale lines
    __syncthreads();
}

__global__ __launch_bounds__(256, 2) void mega_kernel(MegaArgs A)
{
    __shared__ __align__(16) float smem[8704];   // 34.8 KB
    int bid = blockIdx.x, tid = threadIdx.x;

    // ================= Phase A =================
    for (int t = bid; t < 2560; t += GRID_BLKS) {   // 5 iterations, uniform
        __syncthreads();
        if (t < 1408) {
            // ---- projection: 8 rows per task ----
            int task, mblk;
            if (t < 896) { task = t >> 7; mblk = t & 127; }
            else { int r = t - 896; task = 7 + (r >> 8); mblk = r & 255; }
            int Kd = A.Kdim[task];
            const float* x = A.x[task];
            int m0 = mblk * 8;
            if (Kd == 128) {
                ((float4*)smem)[tid] = ((const float4*)(x + (size_t)m0 * 128))[tid];
            } else {
                for (int i = tid; i < 1024; i += 256) {
                    int r = i >> 7, c = i & 127;
                    smem[i] = (c < Kd) ? x[(size_t)(m0 + r) * Kd + c] : 0.f;
                }
            }
            __syncthreads();
            int e = tid & 127, half = tid >> 7;
            const float4* w4 = (const float4*)(A.W[task] + (size_t)e * 128);
            const float4* xs4 = (const float4*)smem + half * 4 * 32;
            float acc[4];
            float bv = A.bia[task][e];
#pragma unroll
            for (int r = 0; r < 4; ++r) acc[r] = bv;
#pragma unroll 8
            for (int c = 0; c < 32; ++c) {
                float4 w = w4[c];
#pragma unroll
                for (int r = 0; r < 4; ++r) {
                    float4 xv = xs4[r * 32 + c];
                    acc[r] += w.x * xv.x + w.y * xv.y + w.z * xv.z + w.w * xv.w;
                }
            }
            int nb = A.transNb[task];
            float* op = A.out[task];
            if (nb == 0) {
#pragma unroll
                for (int r = 0; r < 4; ++r)
                    op[(size_t)(m0 + half * 4 + r) * 128 + e] = acc[r];
            } else {
                int b = m0 / nb, nloc = m0 - b * nb;
                float* o = op + ((size_t)b * 128 + e) * nb + nloc + half * 4;
                float4 v = { acc[0], acc[1], acc[2], acc[3] };
                *(float4*)o = v;
            }
        } else if (t < 2432) {
            // ---- CI transpose: cit[b][c][n] = CIMat[b][n][c] ----
            int tb = t - 1408;
            int b = tb >> 8, tt = tb & 255;
            int n0 = (tt >> 4) * 32, c0 = (tt & 15) * 32;
            float (*tile)[33] = (float(*)[33])smem;
            int tx = tid & 31, ty = tid >> 5;   // 32 x 8
            const float* src = A.CIMat + (size_t)b * 262144;
            float* dst = A.cit + (size_t)b * 262144;
#pragma unroll
            for (int i = ty; i < 32; i += 8)
                tile[i][tx] = src[(size_t)(n0 + i) * 512 + c0 + tx];
            __syncthreads();
#pragma unroll
            for (int i = ty; i < 32; i += 8)
                dst[(size_t)(c0 + i) * 512 + n0 + tx] = tile[tx][i];
        } else {
            // ---- fold out-projections into dim projection ----
            float* ds = smem;
            float* red = smem + 384;
            int e = t - 2432, k = tid;
            if (k < 128) {
                ds[k]       = A.dim_w[(size_t)e * 384 + k];
                ds[128 + k] = A.dim_w[(size_t)e * 384 + 128 + k];
                ds[256 + k] = A.dim_w[(size_t)e * 384 + 256 + k];
            }
            __syncthreads();
            if (k < 128) {
                float cu = 0.f, ct = 0.f, cd = 0.f;
#pragma unroll 4
                for (int j = 0; j < 128; ++j) {
                    cu += ds[j]       * A.uu_ow[(size_t)j * 128 + k];
                    ct += ds[128 + j] * A.ta_ow[(size_t)j * 128 + k];
                    cd += ds[256 + j] * A.du_ow[(size_t)j * 128 + k];
                }
                A.Cuu[(size_t)e * 128 + k] = cu;
                A.Cta[(size_t)e * 128 + k] = ct;
                A.Cdu[(size_t)e * 128 + k] = cd;
                red[k] = ds[k] * A.uu_ob[k] + ds[128 + k] * A.ta_ob[k] + ds[256 + k] * A.du_ob[k];
            }
            __syncthreads();
            for (int off = 64; off; off >>= 1) {
                if (k < off) red[k] += red[k + off];
                __syncthreads();
            }
            if (k == 0) A.bcomb[e] = A.dim_b[e] + red[0];
        }
    }
    grid_bar(A.flags, 1u);

    // ================= Phase B =================
    for (int t = bid; t < 2048; t += GRID_BLKS) {   // 4 iterations, uniform
        __syncthreads();
        if (t < 1024) {
            // ---- attn256 (kind 0 = ta, 1 = du): 2 heads x 8 query rows ----
            int kind = t >> 9, idx = t & 511;
            const float* q  = kind ? A.qdu  : A.qta;
            const float* kT = kind ? A.kduT : A.ktaT;
            const float* v  = kind ? A.vdu  : A.vta;
            float* o        = kind ? A.odu  : A.ota;
            int hg = idx & 3, lt = (idx >> 2) & 31, b = idx >> 7;
            int l0 = lt * 8, bl0 = b * 256 + l0;
            float* qs = smem;            // 256
            float* sc = smem + 256;      // 16*256
            float* den = smem + 4352;    // 16
            {
                int l = tid >> 5, d = tid & 31;
                qs[l * 32 + d] = q[(size_t)(bl0 + l) * 128 + hg * 32 + d];
            }
            __syncthreads();
            {
                int n = tid;
                const float* kp = kT + ((size_t)b * 128 + hg * 32) * 256 + n;
                float acc[8][2];
#pragma unroll
                for (int l = 0; l < 8; ++l) { acc[l][0] = 0.f; acc[l][1] = 0.f; }
#pragma unroll 8
                for (int d = 0; d < 32; ++d) {
                    float kv = kp[(size_t)d * 256];
                    int hl = d >> 4;
#pragma unroll
                    for (int l = 0; l < 8; ++l) acc[l][hl] += qs[l * 32 + d] * kv;
                }
#pragma unroll
                for (int hl = 0; hl < 2; ++hl)
#pragma unroll
                    for (int l = 0; l < 8; ++l)
                        sc[(hl * 8 + l) * 256 + n] = acc[l][hl] * 0.25f;
            }
            __syncthreads();
            {
                int g = tid >> 4, j = tid & 15;
                float* row = sc + g * 256;
                float mx = -1e30f;
#pragma unroll 4
                for (int n = j; n < 256; n += 16) mx = fmaxf(mx, row[n]);
#pragma unroll
                for (int off = 8; off; off >>= 1) mx = fmaxf(mx, __shfl_down(mx, off, 16));
                mx = __shfl(mx, 0, 16);
                float s = 0.f;
#pragma unroll 4
                for (int n = j; n < 256; n += 16) {
                    float ev = __expf(row[n] - mx);
                    row[n] = ev; s += ev;
                }
#pragma unroll
                for (int off = 8; off; off >>= 1) s += __shfl_down(s, off, 16);
                if (j == 0) den[g] = s;
            }
            __syncthreads();
            {
                int col = tid & 31, l = tid >> 5;
                int colglob = hg * 32 + col;
                int g = (col >> 4) * 8 + l;
                const float* vcol = v + (size_t)b * 256 * 128 + colglob;
                const float* p = sc + g * 256;
                float acc = 0.f;
#pragma unroll 4
                for (int n = 0; n < 256; ++n) acc += p[n] * vcol[(size_t)n * 128];
                o[(size_t)(bl0 + l) * 128 + colglob] = acc / den[g];
            }
        } else {
            // ---- attn_uu: 2 heads x 4 query rows, N=512, rank-2 ci correction ----
            int idx = t - 1024;
            int hg = idx & 3, lt = (idx >> 2) & 63, b = idx >> 8;
            int l0 = lt * 4, bl0 = b * 256 + l0;
            float* qs   = smem;            // 128
            float* sc   = smem + 128;      // 8*512
            float* ci0s = smem + 4224;     // 2048
            float* ci1s = smem + 6272;     // 2048
            float* qkA  = smem + 8320;     // 8
            float* qkB  = smem + 8328;
            float* den  = smem + 8336;
            float* hs0  = smem + 8344;
            float* hs1  = smem + 8352;
            float* vpart = smem + 8360;    // 256
            if (tid < 128) {
                int l = tid >> 5, d = tid & 31;
                qs[l * 32 + d] = A.qd[(size_t)(bl0 + l) * 128 + hg * 32 + d];
            }
            {
                const float4* s0 = (const float4*)(A.cit + ((size_t)b * 512 + l0) * 512);
                const float4* s1 = (const float4*)(A.cit + ((size_t)b * 512 + 256 + l0) * 512);
                ((float4*)ci0s)[tid] = s0[tid];  ((float4*)ci0s)[tid + 256] = s0[tid + 256];
                ((float4*)ci1s)[tid] = s1[tid];  ((float4*)ci1s)[tid + 256] = s1[tid + 256];
            }
            __syncthreads();
            if (tid < 8) {
                int hl = tid >> 2, l = tid & 3;
                float a = 0.f, c = 0.f;
#pragma unroll
                for (int d = 0; d < 16; ++d) {
                    float qv = qs[l * 32 + hl * 16 + d];
                    int wr = 128 + hg * 32 + hl * 16 + d;
                    a += qv * A.uu_in_w[(size_t)wr * 128 + 126];
                    c += qv * A.uu_in_w[(size_t)wr * 128 + 127];
                }
                qkA[tid] = a; qkB[tid] = c;
            }
            __syncthreads();
            {
                const float* kp = A.kbaseT + ((size_t)b * 128 + hg * 32) * 512 + tid;
                float acc[2][4][2];
#pragma unroll
                for (int r = 0; r < 2; ++r)
#pragma unroll
                    for (int l = 0; l < 4; ++l) { acc[r][l][0] = 0.f; acc[r][l][1] = 0.f; }
#pragma unroll 8
                for (int d = 0; d < 32; ++d) {
                    float kv0 = kp[(size_t)d * 512];
                    float kv1 = kp[(size_t)d * 512 + 256];
                    int hl = d >> 4;
#pragma unroll
                    for (int l = 0; l < 4; ++l) {
                        float qv = qs[l * 32 + d];
                        acc[0][l][hl] += qv * kv0;
                        acc[1][l][hl] += qv * kv1;
                    }
                }
#pragma unroll
                for (int r = 0; r < 2; ++r) {
                    int n = tid + r * 256;
#pragma unroll
                    for (int l = 0; l < 4; ++l) {
                        float c0 = ci0s[l * 512 + n], c1 = ci1s[l * 512 + n];
#pragma unroll
                        for (int hl = 0; hl < 2; ++hl) {
                            int g = hl * 4 + l;
                            sc[g * 512 + n] = (acc[r][l][hl] + c0 * qkA[g] + c1 * qkB[g]) * 0.25f;
                        }
                    }
                }
            }
            __syncthreads();
            {
                int g = tid >> 5, j = tid & 31;
                int l = g & 3;
                float* row = sc + g * 512;
                const float* c0r = ci0s + l * 512;
                const float* c1r = ci1s + l * 512;
                float mx = -1e30f;
#pragma unroll 4
                for (int n = j; n < 512; n += 32) mx = fmaxf(mx, row[n]);
#pragma unroll
                for (int off = 16; off; off >>= 1) mx = fmaxf(mx, __shfl_down(mx, off, 32));
                mx = __shfl(mx, 0, 32);
                float s = 0.f, a0 = 0.f, a1 = 0.f;
#pragma unroll 4
                for (int n = j; n < 512; n += 32) {
                    float ev = __expf(row[n] - mx);
                    row[n] = ev;
                    s += ev; a0 += ev * c0r[n]; a1 += ev * c1r[n];
                }
#pragma unroll
                for (int off = 16; off; off >>= 1) {
                    s  += __shfl_down(s, off, 32);
                    a0 += __shfl_down(a0, off, 32);
                    a1 += __shfl_down(a1, off, 32);
                }
                if (j == 0) { den[g] = s; hs0[g] = a0; hs1[g] = a1; }
            }
            __syncthreads();
            {
                int col = tid & 31, l = (tid >> 5) & 3, half = tid >> 7;
                int colglob = hg * 32 + col;
                int g = (col >> 4) * 4 + l;
                const float* vcol = A.vbase + ((size_t)b * 512 + half * 256) * 128 + colglob;
                const float* p = sc + g * 512 + half * 256;
                float acc = 0.f;
#pragma unroll 4
                for (int n = 0; n < 256; ++n) acc += p[n] * vcol[(size_t)n * 128];
                vpart[half * 128 + (tid & 127)] = acc;
            }
            __syncthreads();
            if (tid < 128) {
                int col = tid & 31, l = tid >> 5;
                int colglob = hg * 32 + col;
                int g = (col >> 4) * 4 + l;
                float sum = vpart[tid] + vpart[128 + tid];
                float wv126 = A.uu_in_w[(size_t)(256 + colglob) * 128 + 126];
                float wv127 = A.uu_in_w[(size_t)(256 + colglob) * 128 + 127];
                A.ouu[(size_t)(bl0 + l) * 128 + colglob] =
                    (sum + hs0[g] * wv126 + hs1[g] * wv127) / den[g];
            }
        }
    }
    grid_bar(A.flags, 2u);

    // ================= Phase C: epilogue (held in registers) + BN stats =================
    float accC[2] = { 0.f, 0.f };
    int eC = tid & 127, halfC = tid >> 7, m0C = bid * 4;
    if (bid < 256) {
        __syncthreads();
        float* xs = smem;   // 4 rows x 384
        for (int i = tid; i < 1536; i += 256) {
            int r = i / 384, c = i - r * 384;
            float v;
            if (c < 128)      v = A.ouu[(size_t)(m0C + r) * 128 + c];
            else if (c < 256) v = A.ota[(size_t)(m0C + r) * 128 + c - 128];
            else              v = A.odu[(size_t)(m0C + r) * 128 + c - 256];
            xs[i] = v;
        }
        __syncthreads();
        const float4* cu4 = (const float4*)(A.Cuu + (size_t)eC * 128);
        const float4* ct4 = (const float4*)(A.Cta + (size_t)eC * 128);
        const float4* cd4 = (const float4*)(A.Cdu + (size_t)eC * 128);
        const float4* xs4 = (const float4*)xs;   // row pitch 96 float4
        float bc = A.bcomb[eC];
        accC[0] = bc; accC[1] = bc;
        int r0 = halfC * 2;
#pragma unroll 4
        for (int c = 0; c < 32; ++c) {
            float4 a = cu4[c], bb = ct4[c], d = cd4[c];
#pragma unroll
            for (int rr = 0; rr < 2; ++rr) {
                float4 xu = xs4[(r0 + rr) * 96 + c];
                float4 xt = xs4[(r0 + rr) * 96 + 32 + c];
                float4 xd = xs4[(r0 + rr) * 96 + 64 + c];
                accC[rr] += a.x * xu.x + a.y * xu.y + a.z * xu.z + a.w * xu.w
                          + bb.x * xt.x + bb.y * xt.y + bb.z * xt.z + bb.w * xt.w
                          + d.x * xd.x + d.y * xd.y + d.z * xd.z + d.w * xd.w;
            }
        }
        atomicAdd(A.gstat + eC, accC[0] + accC[1]);
        atomicAdd(A.gstat + 128 + eC, accC[0] * accC[0] + accC[1] * accC[1]);
    }
    grid_bar(A.flags, 3u);

    // ================= Phase D: BN apply + ReLU =================
    if (bid < 256) {
        float mean = A.gstat[eC] * (1.f / 1024.f);
        float var  = A.gstat[128 + eC] * (1.f / 1024.f) - mean * mean;
        float inv  = rsqrtf(var + 1e-5f);
        float g = A.bn_g[eC], bt = A.bn_b[eC];
        int r0 = halfC * 2;
#pragma unroll
        for (int rr = 0; rr < 2; ++rr)
            A.outp[(size_t)(m0C + r0 + rr) * 128 + eC] =
                fmaxf((accC[rr] - mean) * inv * g + bt, 0.f);
    }
}

extern "C" void kernel_launch(void* const* d_in, const int* in_sizes, int n_in,
                              void* d_out, int out_size, void* d_ws, size_t ws_size,
                              hipStream_t stream)
{
    (void)in_sizes; (void)n_in; (void)out_size; (void)ws_size;
    const float* UUMat    = (const float*)d_in[0];
    const float* DUMat    = (const float*)d_in[1];
    const float* TAMat    = (const float*)d_in[2];
    const float* CIMat    = (const float*)d_in[3];
    const float* uu_in_w  = (const float*)d_in[4];
    const float* uu_in_b  = (const float*)d_in[5];
    const float* uu_out_w = (const float*)d_in[6];
    const float* uu_out_b = (const float*)d_in[7];
    const float* ta_in_w  = (const float*)d_in[8];
    const float* ta_in_b  = (const float*)d_in[9];
    const float* ta_out_w = (const float*)d_in[10];
    const float* ta_out_b = (const float*)d_in[11];
    const float* du_in_w  = (const float*)d_in[12];
    const float* du_in_b  = (const float*)d_in[13];
    const float* du_out_w = (const float*)d_in[14];
    const float* du_out_b = (const float*)d_in[15];
    const float* dim_w    = (const float*)d_in[16];
    const float* dim_b    = (const float*)d_in[17];
    const float* bn_g     = (const float*)d_in[18];
    const float* bn_b     = (const float*)d_in[19];

    const int BL = 1024, BN = 2048;
    float* ws0 = (float*)d_ws;
    unsigned* flags = (unsigned*)ws0;             // 512 u32
    float* gstat  = ws0 + 512;                    // 256 floats
    float* ws     = ws0 + 512 + 256;
    float* cit    = ws; ws += (size_t)4 * 512 * 512;
    float* qd     = ws; ws += (size_t)BL * 128;
    float* kbaseT = ws; ws += (size_t)BN * 128;   // [b][128][512]
    float* vbase  = ws; ws += (size_t)BN * 128;
    float* qta    = ws; ws += (size_t)BL * 128;
    float* ktaT   = ws; ws += (size_t)BL * 128;   // [b][128][256]
    float* vta    = ws; ws += (size_t)BL * 128;
    float* qdu    = ws; ws += (size_t)BL * 128;
    float* kduT   = ws; ws += (size_t)BL * 128;   // [b][128][256]
    float* vdu    = ws; ws += (size_t)BL * 128;
    float* ouu    = ws; ws += (size_t)BL * 128;
    float* ota    = ws; ws += (size_t)BL * 128;
    float* odu    = ws; ws += (size_t)BL * 128;
    float* Cuu    = ws; ws += 128 * 128;
    float* Cta    = ws; ws += 128 * 128;
    float* Cdu    = ws; ws += 128 * 128;
    float* bcomb  = ws; ws += 128;

    MegaArgs A;
    A.x[0] = DUMat; A.W[0] = uu_in_w;             A.bia[0] = uu_in_b;       A.out[0] = qd;     A.Kdim[0] = 128; A.transNb[0] = 0;
    A.x[1] = DUMat; A.W[1] = ta_in_w;             A.bia[1] = ta_in_b;       A.out[1] = qta;    A.Kdim[1] = 128; A.transNb[1] = 0;
    A.x[2] = TAMat; A.W[2] = ta_in_w + 128 * 128; A.bia[2] = ta_in_b + 128; A.out[2] = ktaT;   A.Kdim[2] = 128; A.transNb[2] = 256;
    A.x[3] = TAMat; A.W[3] = ta_in_w + 256 * 128; A.bia[3] = ta_in_b + 256; A.out[3] = vta;    A.Kdim[3] = 128; A.transNb[3] = 0;
    A.x[4] = DUMat; A.W[4] = du_in_w;             A.bia[4] = du_in_b;       A.out[4] = qdu;    A.Kdim[4] = 128; A.transNb[4] = 0;
    A.x[5] = DUMat; A.W[5] = du_in_w + 128 * 128; A.bia[5] = du_in_b + 128; A.out[5] = kduT;   A.Kdim[5] = 128; A.transNb[5] = 256;
    A.x[6] = DUMat; A.W[6] = du_in_w + 256 * 128; A.bia[6] = du_in_b + 256; A.out[6] = vdu;    A.Kdim[6] = 128; A.transNb[6] = 0;
    A.x[7] = UUMat; A.W[7] = uu_in_w + 128 * 128; A.bia[7] = uu_in_b + 128; A.out[7] = kbaseT; A.Kdim[7] = 126; A.transNb[7] = 512;
    A.x[8] = UUMat; A.W[8] = uu_in_w + 256 * 128; A.bia[8] = uu_in_b + 256; A.out[8] = vbase;  A.Kdim[8] = 126; A.transNb[8] = 0;
    A.CIMat = CIMat; A.cit = cit;
    A.dim_w = dim_w; A.dim_b = dim_b;
    A.uu_ow = uu_out_w; A.uu_ob = uu_out_b;
    A.ta_ow = ta_out_w; A.ta_ob = ta_out_b;
    A.du_ow = du_out_w; A.du_ob = du_out_b;
    A.Cuu = Cuu; A.Cta = Cta; A.Cdu = Cdu; A.bcomb = bcomb;
    A.qd = qd; A.kbaseT = kbaseT; A.vbase = vbase;
    A.qta = qta; A.ktaT = ktaT; A.vta = vta;
    A.qdu = qdu; A.kduT = kduT; A.vdu = vdu;
    A.ouu = ouu; A.ota = ota; A.odu = odu;
    A.uu_in_w = uu_in_w;
    A.gstat = gstat;
    A.flags = flags;
    A.bn_g = bn_g; A.bn_b = bn_b;
    A.outp = (float*)d_out;

    // zero per-block flags + BN stat accumulators (ws is poisoned 0xAA before every call)
    hipMemsetAsync(d_ws, 0, (512 + 256) * sizeof(float), stream);

    hipLaunchKernelGGL(mega_kernel, dim3(GRID_BLKS), dim3(256), 0, stream, A);
}

// Round 9
// 211.470 us; speedup vs baseline: 2.7258x; 1.9464x over previous
//
#include <hip/hip_runtime.h>

// B=4, L=256, E=128, H=8, D=16, NU=512, NT=256. All I/O fp32.
// 3 dispatches (inter-dispatch stream order provides the only 2 syncs needed):
//   1. pre_fused : 9 projections (K transposed) + CI transpose + weight-fold + gstat zero
//   2. attn_epi  : per 2 query rows: ta + du + uu attention (ALL heads) -> cat in LDS
//                  -> epilogue y = C @ cat + bias -> BN stat atomics
//   3. bn_apply  : (y - mean)*rsqrt(var+eps)*g + b, ReLU

struct PreArgs {
    const float* x[9]; const float* W[9]; const float* bia[9]; float* out[9];
    int Kdim[9]; int transNb[9];     // 0 = row-major out; else n-per-b for [b][e][n] layout
    const float* CIMat; float* cit;
    const float* dim_w; const float* dim_b;
    const float* uu_ow; const float* uu_ob;
    const float* ta_ow; const float* ta_ob;
    const float* du_ow; const float* du_ob;
    float* Cuu; float* Cta; float* Cdu; float* bcomb;
    float* gstat;                    // 256 floats (zeroed here, used by dispatch 2/3)
};

// tasks: [0,1408) proj (8 rows each), [1408,2432) CI transpose, [2432,2560) fold
__global__ __launch_bounds__(256) void pre_fused(PreArgs A)
{
    __shared__ __align__(16) float smem[1056];
    int bid = blockIdx.x, tid = threadIdx.x;
    if (bid == 0) A.gstat[tid] = 0.f;

    if (bid < 1408) {
        int task, mblk;
        if (bid < 896) { task = bid >> 7; mblk = bid & 127; }
        else { int r = bid - 896; task = 7 + (r >> 8); mblk = r & 255; }
        int Kd = A.Kdim[task];
        const float* x = A.x[task];
        int m0 = mblk * 8;
        if (Kd == 128) {
            ((float4*)smem)[tid] = ((const float4*)(x + (size_t)m0 * 128))[tid];
        } else {
            for (int i = tid; i < 1024; i += 256) {
                int r = i >> 7, c = i & 127;
                smem[i] = (c < Kd) ? x[(size_t)(m0 + r) * Kd + c] : 0.f;
            }
        }
        __syncthreads();
        int e = tid & 127, half = tid >> 7;
        const float4* w4 = (const float4*)(A.W[task] + (size_t)e * 128);
        const float4* xs4 = (const float4*)smem + half * 4 * 32;
        float acc[4];
        float bv = A.bia[task][e];
#pragma unroll
        for (int r = 0; r < 4; ++r) acc[r] = bv;
#pragma unroll 8
        for (int c = 0; c < 32; ++c) {
            float4 w = w4[c];
#pragma unroll
            for (int r = 0; r < 4; ++r) {
                float4 xv = xs4[r * 32 + c];
                acc[r] += w.x * xv.x + w.y * xv.y + w.z * xv.z + w.w * xv.w;
            }
        }
        int nb = A.transNb[task];
        float* op = A.out[task];
        if (nb == 0) {
#pragma unroll
            for (int r = 0; r < 4; ++r)
                op[(size_t)(m0 + half * 4 + r) * 128 + e] = acc[r];
        } else {
            int b = m0 / nb, nloc = m0 - b * nb;
            float* o = op + ((size_t)b * 128 + e) * nb + nloc + half * 4;
            float4 v = { acc[0], acc[1], acc[2], acc[3] };
            *(float4*)o = v;
        }
    } else if (bid < 2432) {
        int tb = bid - 1408;
        int b = tb >> 8, tt = tb & 255;
        int n0 = (tt >> 4) * 32, c0 = (tt & 15) * 32;
        float (*tile)[33] = (float(*)[33])smem;
        int tx = tid & 31, ty = tid >> 5;   // 32 x 8
        const float* src = A.CIMat + (size_t)b * 262144;
        float* dst = A.cit + (size_t)b * 262144;
#pragma unroll
        for (int i = ty; i < 32; i += 8)
            tile[i][tx] = src[(size_t)(n0 + i) * 512 + c0 + tx];
        __syncthreads();
#pragma unroll
        for (int i = ty; i < 32; i += 8)
            dst[(size_t)(c0 + i) * 512 + n0 + tx] = tile[tx][i];
    } else {
        float* ds = smem;
        float* red = smem + 384;
        int e = bid - 2432, k = tid;
        if (k < 128) {
            ds[k]       = A.dim_w[(size_t)e * 384 + k];
            ds[128 + k] = A.dim_w[(size_t)e * 384 + 128 + k];
            ds[256 + k] = A.dim_w[(size_t)e * 384 + 256 + k];
        }
        __syncthreads();
        if (k < 128) {
            float cu = 0.f, ct = 0.f, cd = 0.f;
#pragma unroll 4
            for (int j = 0; j < 128; ++j) {
                cu += ds[j]       * A.uu_ow[(size_t)j * 128 + k];
                ct += ds[128 + j] * A.ta_ow[(size_t)j * 128 + k];
                cd += ds[256 + j] * A.du_ow[(size_t)j * 128 + k];
            }
            A.Cuu[(size_t)e * 128 + k] = cu;
            A.Cta[(size_t)e * 128 + k] = ct;
            A.Cdu[(size_t)e * 128 + k] = cd;
            red[k] = ds[k] * A.uu_ob[k] + ds[128 + k] * A.ta_ob[k] + ds[256 + k] * A.du_ob[k];
        }
        __syncthreads();
        for (int off = 64; off; off >>= 1) {
            if (k < off) red[k] += red[k + off];
            __syncthreads();
        }
        if (k == 0) A.bcomb[e] = A.dim_b[e] + red[0];
    }
}

struct AttnArgs {
    const float* qd; const float* kbaseT; const float* vbase; const float* cit;
    const float* qta; const float* ktaT; const float* vta;
    const float* qdu; const float* kduT; const float* vdu;
    const float* uu_in_w;
    const float* Cuu; const float* Cta; const float* Cdu; const float* bcomb;
    float* y; float* gstat;
};

// LDS layout (floats): QS 0..256 | SC 256..8448 | CI0 8448..9472 | CI1 9472..10496
//                      CAT 10496..11264 | MISC 11264..11344   (VPART/STAT reuse CI0/CI1)
__global__ __launch_bounds__(256) void attn_epi(AttnArgs A)
{
    __shared__ __align__(16) float smem[11344];   // 45.4 KB
    int bid = blockIdx.x, tid = threadIdx.x;
    int b = bid >> 7, l0 = (bid & 127) * 2, bl0 = b * 256 + l0;
    float*  qs   = smem;
    float2* sc2  = (float2*)(smem + 256);
    float*  ci0s = smem + 8448;
    float*  ci1s = smem + 9472;
    float*  vpart = smem + 8448;    // reused after ci consumed
    float*  cat  = smem + 10496;    // [2 rows][384]
    float*  den  = smem + 11264;    // [h*2+l]
    float*  hs0  = den + 16;
    float*  hs1  = hs0 + 16;
    float*  qkA  = hs1 + 16;        // [h*2+l]
    float*  qkB  = qkA + 16;

    // ================= ta and du stages (N=256) =================
    for (int kind = 0; kind < 2; ++kind) {
        const float* q  = kind ? A.qdu  : A.qta;
        const float* kT = kind ? A.kduT : A.ktaT;
        const float* v  = kind ? A.vdu  : A.vta;
        int catoff = 128 + kind * 128;
        __syncthreads();
        { int l = tid >> 7, d = tid & 127; qs[l * 128 + d] = q[(size_t)(bl0 + l) * 128 + d]; }
        __syncthreads();
        {   // scores: thread = key n
            int n = tid;
            const float* kp = kT + (size_t)b * 128 * 256 + n;
            float acc[2][8];
#pragma unroll
            for (int h = 0; h < 8; ++h) { acc[0][h] = 0.f; acc[1][h] = 0.f; }
#pragma unroll
            for (int h = 0; h < 8; ++h)
#pragma unroll
                for (int d = 0; d < 16; ++d) {
                    float kv = kp[(size_t)(h * 16 + d) * 256];
                    acc[0][h] += qs[h * 16 + d] * kv;
                    acc[1][h] += qs[128 + h * 16 + d] * kv;
                }
#pragma unroll
            for (int h = 0; h < 8; ++h) {
                float2 s = { acc[0][h] * 0.25f, acc[1][h] * 0.25f };
                sc2[h * 256 + n] = s;
            }
        }
        __syncthreads();
        {   // softmax: 8 head-groups x 32 lanes, both rows via float2
            int g = tid >> 5, j = tid & 31;
            float2* row = sc2 + g * 256;
            float2 mx = { -1e30f, -1e30f };
#pragma unroll
            for (int n = j; n < 256; n += 32) {
                float2 vv = row[n];
                mx.x = fmaxf(mx.x, vv.x); mx.y = fmaxf(mx.y, vv.y);
            }
#pragma unroll
            for (int off = 16; off; off >>= 1) {
                mx.x = fmaxf(mx.x, __shfl_down(mx.x, off, 32));
                mx.y = fmaxf(mx.y, __shfl_down(mx.y, off, 32));
            }
            mx.x = __shfl(mx.x, 0, 32); mx.y = __shfl(mx.y, 0, 32);
            float2 s = { 0.f, 0.f };
#pragma unroll
            for (int n = j; n < 256; n += 32) {
                float2 vv = row[n];
                vv.x = __expf(vv.x - mx.x); vv.y = __expf(vv.y - mx.y);
                row[n] = vv;
                s.x += vv.x; s.y += vv.y;
            }
#pragma unroll
            for (int off = 16; off; off >>= 1) {
                s.x += __shfl_down(s.x, off, 32); s.y += __shfl_down(s.y, off, 32);
            }
            if (j == 0) { den[g * 2] = s.x; den[g * 2 + 1] = s.y; }
        }
        __syncthreads();
        {   // V pass partials: col x n-half
            int col = tid & 127, nh = tid >> 7, h = col >> 4;
            const float* vcol = v + ((size_t)b * 256 + nh * 128) * 128 + col;
            const float2* p = sc2 + h * 256 + nh * 128;
            float a0 = 0.f, a1 = 0.f;
#pragma unroll 4
            for (int n = 0; n < 128; ++n) {
                float vv = vcol[(size_t)n * 128];
                float2 pp = p[n];
                a0 += pp.x * vv; a1 += pp.y * vv;
            }
            vpart[nh * 256 + col * 2]     = a0;
            vpart[nh * 256 + col * 2 + 1] = a1;
        }
        __syncthreads();
        {
            int col = tid & 127, l = tid >> 7, h = col >> 4;
            float sum = vpart[col * 2 + l] + vpart[256 + col * 2 + l];
            cat[l * 384 + catoff + col] = sum / den[h * 2 + l];
        }
    }

    // ================= uu stage (N=512, rank-2 ci correction) =================
    __syncthreads();
    { int l = tid >> 7, d = tid & 127; qs[l * 128 + d] = A.qd[(size_t)(bl0 + l) * 128 + d]; }
    {   // ci rows contiguous in cit
        const float4* s0 = (const float4*)(A.cit + ((size_t)b * 512 + l0) * 512);
        const float4* s1 = (const float4*)(A.cit + ((size_t)b * 512 + 256 + l0) * 512);
        ((float4*)ci0s)[tid] = s0[tid];
        ((float4*)ci1s)[tid] = s1[tid];
    }
    __syncthreads();
    if (tid < 16) {
        int h = tid >> 1, l = tid & 1;
        float a = 0.f, c = 0.f;
#pragma unroll
        for (int d = 0; d < 16; ++d) {
            float qv = qs[l * 128 + h * 16 + d];
            a += qv * A.uu_in_w[(size_t)(128 + h * 16 + d) * 128 + 126];
            c += qv * A.uu_in_w[(size_t)(128 + h * 16 + d) * 128 + 127];
        }
        qkA[tid] = a; qkB[tid] = c;
    }
    __syncthreads();
    {   // scores: thread covers n = tid and tid+256
        const float* kp = A.kbaseT + (size_t)b * 128 * 512 + tid;
        float acc[2][2][8];   // [nh][l][h]
#pragma unroll
        for (int nh = 0; nh < 2; ++nh)
#pragma unroll
            for (int h = 0; h < 8; ++h) { acc[nh][0][h] = 0.f; acc[nh][1][h] = 0.f; }
#pragma unroll
        for (int h = 0; h < 8; ++h)
#pragma unroll
            for (int d = 0; d < 16; ++d) {
                float kv0 = kp[(size_t)(h * 16 + d) * 512];
                float kv1 = kp[(size_t)(h * 16 + d) * 512 + 256];
                float q0 = qs[h * 16 + d], q1 = qs[128 + h * 16 + d];
                acc[0][0][h] += q0 * kv0; acc[0][1][h] += q1 * kv0;
                acc[1][0][h] += q0 * kv1; acc[1][1][h] += q1 * kv1;
            }
#pragma unroll
        for (int nh = 0; nh < 2; ++nh) {
            int n = tid + nh * 256;
            float c00 = ci0s[n], c01 = ci0s[512 + n];
            float c10 = ci1s[n], c11 = ci1s[512 + n];
#pragma unroll
            for (int h = 0; h < 8; ++h) {
                float2 s;
                s.x = (acc[nh][0][h] + c00 * qkA[h * 2]     + c10 * qkB[h * 2])     * 0.25f;
                s.y = (acc[nh][1][h] + c01 * qkA[h * 2 + 1] + c11 * qkB[h * 2 + 1]) * 0.25f;
                sc2[h * 512 + n] = s;
            }
        }
    }
    __syncthreads();
    {   // softmax + ci-weighted sums over 512
        int g = tid >> 5, j = tid & 31;
        float2* row = sc2 + g * 512;
        float2 mx = { -1e30f, -1e30f };
#pragma unroll
        for (int n = j; n < 512; n += 32) {
            float2 vv = row[n];
            mx.x = fmaxf(mx.x, vv.x); mx.y = fmaxf(mx.y, vv.y);
        }
#pragma unroll
        for (int off = 16; off; off >>= 1) {
            mx.x = fmaxf(mx.x, __shfl_down(mx.x, off, 32));
            mx.y = fmaxf(mx.y, __shfl_down(mx.y, off, 32));
        }
        mx.x = __shfl(mx.x, 0, 32); mx.y = __shfl(mx.y, 0, 32);
        float2 s = { 0.f, 0.f }, a0 = { 0.f, 0.f }, a1 = { 0.f, 0.f };
#pragma unroll
        for (int n = j; n < 512; n += 32) {
            float2 vv = row[n];
            vv.x = __expf(vv.x - mx.x); vv.y = __expf(vv.y - mx.y);
            row[n] = vv;
            s.x += vv.x; s.y += vv.y;
            a0.x += vv.x * ci0s[n]; a0.y += vv.y * ci0s[512 + n];
            a1.x += vv.x * ci1s[n]; a1.y += vv.y * ci1s[512 + n];
        }
#pragma unroll
        for (int off = 16; off; off >>= 1) {
            s.x  += __shfl_down(s.x, off, 32);  s.y  += __shfl_down(s.y, off, 32);
            a0.x += __shfl_down(a0.x, off, 32); a0.y += __shfl_down(a0.y, off, 32);
            a1.x += __shfl_down(a1.x, off, 32); a1.y += __shfl_down(a1.y, off, 32);
        }
        if (j == 0) {
            den[g * 2] = s.x;  den[g * 2 + 1] = s.y;
            hs0[g * 2] = a0.x; hs0[g * 2 + 1] = a0.y;
            hs1[g * 2] = a1.x; hs1[g * 2 + 1] = a1.y;
        }
    }
    __syncthreads();
    {   // V pass partials (vpart overwrites ci region - ci fully consumed above)
        int col = tid & 127, nh = tid >> 7, h = col >> 4;
        const float* vcol = A.vbase + ((size_t)b * 512 + nh * 256) * 128 + col;
        const float2* p = sc2 + h * 512 + nh * 256;
        float a0 = 0.f, a1 = 0.f;
#pragma unroll 4
        for (int n = 0; n < 256; ++n) {
            float vv = vcol[(size_t)n * 128];
            float2 pp = p[n];
            a0 += pp.x * vv; a1 += pp.y * vv;
        }
        vpart[nh * 256 + col * 2]     = a0;
        vpart[nh * 256 + col * 2 + 1] = a1;
    }
    __syncthreads();
    {
        int col = tid & 127, l = tid >> 7, g = (col >> 4) * 2 + l;
        float sum = vpart[col * 2 + l] + vpart[256 + col * 2 + l];
        float wv126 = A.uu_in_w[(size_t)(256 + col) * 128 + 126];
        float wv127 = A.uu_in_w[(size_t)(256 + col) * 128 + 127];
        cat[l * 384 + col] = (sum + hs0[g] * wv126 + hs1[g] * wv127) / den[g];
    }
    __syncthreads();

    // ================= epilogue: y = C @ cat + bias; BN stat atomics =================
    {
        int e = tid & 127, l = tid >> 7;
        const float4* cu4 = (const float4*)(A.Cuu + (size_t)e * 128);
        const float4* ct4 = (const float4*)(A.Cta + (size_t)e * 128);
        const float4* cd4 = (const float4*)(A.Cdu + (size_t)e * 128);
        const float4* x4 = (const float4*)(cat + l * 384);
        float acc = A.bcomb[e];
#pragma unroll 4
        for (int c = 0; c < 32; ++c) {
            float4 a = cu4[c], bb = ct4[c], d = cd4[c];
            float4 xu = x4[c], xt = x4[32 + c], xd = x4[64 + c];
            acc += a.x * xu.x + a.y * xu.y + a.z * xu.z + a.w * xu.w
                 + bb.x * xt.x + bb.y * xt.y + bb.z * xt.z + bb.w * xt.w
                 + d.x * xd.x + d.y * xd.y + d.z * xd.z + d.w * xd.w;
        }
        A.y[(size_t)(bl0 + l) * 128 + e] = acc;
        vpart[tid] = acc;              // stats LDS-combine (vpart free again)
        vpart[256 + tid] = acc * acc;
        __syncthreads();
        if (tid < 128) {
            atomicAdd(A.gstat + tid, vpart[tid] + vpart[tid + 128]);
            atomicAdd(A.gstat + 128 + tid, vpart[256 + tid] + vpart[256 + tid + 128]);
        }
    }
}

__global__ __launch_bounds__(256) void bn_apply(
    const float* __restrict__ y, const float* __restrict__ gstat,
    const float* __restrict__ gamma, const float* __restrict__ beta,
    float* __restrict__ out)
{
    int gid = blockIdx.x * 256 + threadIdx.x;      // float4 index, 32768 total
    int c0 = (gid & 31) * 4;
    float4 v = ((const float4*)y)[gid];
    float r[4] = { v.x, v.y, v.z, v.w };
#pragma unroll
    for (int k = 0; k < 4; ++k) {
        int c = c0 + k;
        float mean = gstat[c] * (1.f / 1024.f);
        float var = gstat[128 + c] * (1.f / 1024.f) - mean * mean;
        float inv = rsqrtf(var + 1e-5f);
        r[k] = fmaxf((r[k] - mean) * inv * gamma[c] + beta[c], 0.f);
    }
    float4 ov = { r[0], r[1], r[2], r[3] };
    ((float4*)out)[gid] = ov;
}

extern "C" void kernel_launch(void* const* d_in, const int* in_sizes, int n_in,
                              void* d_out, int out_size, void* d_ws, size_t ws_size,
                              hipStream_t stream)
{
    (void)in_sizes; (void)n_in; (void)out_size; (void)ws_size;
    const float* UUMat    = (const float*)d_in[0];
    const float* DUMat    = (const float*)d_in[1];
    const float* TAMat    = (const float*)d_in[2];
    const float* CIMat    = (const float*)d_in[3];
    const float* uu_in_w  = (const float*)d_in[4];
    const float* uu_in_b  = (const float*)d_in[5];
    const float* uu_out_w = (const float*)d_in[6];
    const float* uu_out_b = (const float*)d_in[7];
    const float* ta_in_w  = (const float*)d_in[8];
    const float* ta_in_b  = (const float*)d_in[9];
    const float* ta_out_w = (const float*)d_in[10];
    const float* ta_out_b = (const float*)d_in[11];
    const float* du_in_w  = (const float*)d_in[12];
    const float* du_in_b  = (const float*)d_in[13];
    const float* du_out_w = (const float*)d_in[14];
    const float* du_out_b = (const float*)d_in[15];
    const float* dim_w    = (const float*)d_in[16];
    const float* dim_b    = (const float*)d_in[17];
    const float* bn_g     = (const float*)d_in[18];
    const float* bn_b     = (const float*)d_in[19];

    const int BL = 1024, BN = 2048;
    float* ws = (float*)d_ws;
    float* gstat  = ws; ws += 256;
    float* cit    = ws; ws += (size_t)4 * 512 * 512;
    float* qd     = ws; ws += (size_t)BL * 128;
    float* kbaseT = ws; ws += (size_t)BN * 128;   // [b][128][512]
    float* vbase  = ws; ws += (size_t)BN * 128;
    float* qta    = ws; ws += (size_t)BL * 128;
    float* ktaT   = ws; ws += (size_t)BL * 128;   // [b][128][256]
    float* vta    = ws; ws += (size_t)BL * 128;
    float* qdu    = ws; ws += (size_t)BL * 128;
    float* kduT   = ws; ws += (size_t)BL * 128;   // [b][128][256]
    float* vdu    = ws; ws += (size_t)BL * 128;
    float* yy     = ws; ws += (size_t)BL * 128;
    float* Cuu    = ws; ws += 128 * 128;
    float* Cta    = ws; ws += 128 * 128;
    float* Cdu    = ws; ws += 128 * 128;
    float* bcomb  = ws; ws += 128;

    PreArgs P;
    P.x[0] = DUMat; P.W[0] = uu_in_w;             P.bia[0] = uu_in_b;       P.out[0] = qd;     P.Kdim[0] = 128; P.transNb[0] = 0;
    P.x[1] = DUMat; P.W[1] = ta_in_w;             P.bia[1] = ta_in_b;       P.out[1] = qta;    P.Kdim[1] = 128; P.transNb[1] = 0;
    P.x[2] = TAMat; P.W[2] = ta_in_w + 128 * 128; P.bia[2] = ta_in_b + 128; P.out[2] = ktaT;   P.Kdim[2] = 128; P.transNb[2] = 256;
    P.x[3] = TAMat; P.W[3] = ta_in_w + 256 * 128; P.bia[3] = ta_in_b + 256; P.out[3] = vta;    P.Kdim[3] = 128; P.transNb[3] = 0;
    P.x[4] = DUMat; P.W[4] = du_in_w;             P.bia[4] = du_in_b;       P.out[4] = qdu;    P.Kdim[4] = 128; P.transNb[4] = 0;
    P.x[5] = DUMat; P.W[5] = du_in_w + 128 * 128; P.bia[5] = du_in_b + 128; P.out[5] = kduT;   P.Kdim[5] = 128; P.transNb[5] = 256;
    P.x[6] = DUMat; P.W[6] = du_in_w + 256 * 128; P.bia[6] = du_in_b + 256; P.out[6] = vdu;    P.Kdim[6] = 128; P.transNb[6] = 0;
    P.x[7] = UUMat; P.W[7] = uu_in_w + 128 * 128; P.bia[7] = uu_in_b + 128; P.out[7] = kbaseT; P.Kdim[7] = 126; P.transNb[7] = 512;
    P.x[8] = UUMat; P.W[8] = uu_in_w + 256 * 128; P.bia[8] = uu_in_b + 256; P.out[8] = vbase;  P.Kdim[8] = 126; P.transNb[8] = 0;
    P.CIMat = CIMat; P.cit = cit;
    P.dim_w = dim_w; P.dim_b = dim_b;
    P.uu_ow = uu_out_w; P.uu_ob = uu_out_b;
    P.ta_ow = ta_out_w; P.ta_ob = ta_out_b;
    P.du_ow = du_out_w; P.du_ob = du_out_b;
    P.Cuu = Cuu; P.Cta = Cta; P.Cdu = Cdu; P.bcomb = bcomb;
    P.gstat = gstat;

    AttnArgs T;
    T.qd = qd; T.kbaseT = kbaseT; T.vbase = vbase; T.cit = cit;
    T.qta = qta; T.ktaT = ktaT; T.vta = vta;
    T.qdu = qdu; T.kduT = kduT; T.vdu = vdu;
    T.uu_in_w = uu_in_w;
    T.Cuu = Cuu; T.Cta = Cta; T.Cdu = Cdu; T.bcomb = bcomb;
    T.y = yy; T.gstat = gstat;

    hipLaunchKernelGGL(pre_fused, dim3(2560), dim3(256), 0, stream, P);
    hipLaunchKernelGGL(attn_epi, dim3(512), dim3(256), 0, stream, T);
    hipLaunchKernelGGL(bn_apply, dim3(128), dim3(256), 0, stream,
                       yy, gstat, bn_g, bn_b, (float*)d_out);
}